// Round 2
// baseline (13.631 us; speedup 1.0000x reference)
//
#include <hip/hip_runtime.h>

#define HIDDEN 64

// PairPot: out[i*N+j] = mask ? MLP(|min_image(xyz[j]-xyz[i])|) : 0
//   mask = dis_sq < 2.5^2 && dis_sq != 0
// Fast path (b1 == 0, detected per-wave): MLP(r) = c*r + b2, c = sum_{w1k>0} w1k*w2k.
// Structure: grid-stride over float4 output groups; per-wave barrier-free weight
// reduce (no LDS, no __syncthreads) so no block-granular latency chain.
__global__ __launch_bounds__(256) void PairPot_kernel(
    const float* __restrict__ xyz, const float* __restrict__ cell,
    const float* __restrict__ w1, const float* __restrict__ b1,
    const float* __restrict__ w2, const float* __restrict__ b2,
    float* __restrict__ out, int N, int shift)      // n4 = N/4 = 1<<shift
{
    // ---- per-wave MLP collapse (HIDDEN == 64 == wave size) ----
    const int lane = threadIdx.x & 63;
    const float w1k = w1[lane];
    const float b1k = b1[lane];
    const float w2k = w2[lane];
    float c = (w1k > 0.0f) ? __fmul_rn(w1k, w2k) : 0.0f;
    #pragma unroll
    for (int off = 32; off; off >>= 1) c += __shfl_xor(c, off, 64);   // butterfly: all lanes get sum
    const bool fast = (__ballot(b1k == 0.0f) == ~0ULL);
    const float b2v = b2[0];

    const float cx = cell[0], cy = cell[1], cz = cell[2];
    const float hx = __fmul_rn(0.5f, cx);
    const float hy = __fmul_rn(0.5f, cy);
    const float hz = __fmul_rn(0.5f, cz);

    const int n4m   = (1 << shift) - 1;
    const int total = N << shift;                   // N * n4 float4 groups
    const int stride = gridDim.x * blockDim.x;

    for (int g = blockIdx.x * blockDim.x + threadIdx.x; g < total; g += stride) {
        const int i  = g >> shift;
        const int j0 = (g & n4m) << 2;

        const float xi0 = xyz[3*i+0], xi1 = xyz[3*i+1], xi2 = xyz[3*i+2];

        // 4 particles j0..j0+3 = 12 contiguous floats = 3 coalesced float4 loads
        const float4* pj = reinterpret_cast<const float4*>(xyz + 3*j0);
        const float4 va = pj[0], vb = pj[1], vcc = pj[2];
        const float jx[4] = {va.x, va.w, vb.z, vcc.y};
        const float jy[4] = {va.y, vb.x, vb.w, vcc.z};
        const float jz[4] = {va.z, vb.y, vcc.x, vcc.w};

        float res[4];
        #pragma unroll
        for (int u = 0; u < 4; ++u) {
            // __f*_rn ops forbid fma contraction so the mask decision matches
            // the reference's per-op rounding bit-wise.
            float dx = __fsub_rn(jx[u], xi0);
            float dy = __fsub_rn(jy[u], xi1);
            float dz = __fsub_rn(jz[u], xi2);
            dx = __fadd_rn(dx, (dx >= hx) ? -cx : ((dx < -hx) ? cx : 0.0f));
            dy = __fadd_rn(dy, (dy >= hy) ? -cy : ((dy < -hy) ? cy : 0.0f));
            dz = __fadd_rn(dz, (dz >= hz) ? -cz : ((dz < -hz) ? cz : 0.0f));
            float s = __fadd_rn(__fadd_rn(__fmul_rn(dx, dx), __fmul_rn(dy, dy)),
                                __fmul_rn(dz, dz));
            const bool m = (s < 6.25f) && (s != 0.0f);
            const float r = sqrtf(s);
            float e;
            if (fast) {
                e = fmaf(c, r, b2v);        // exact collapse: b1==0
            } else {
                e = b2v;                    // general fallback (not taken for these inputs)
                #pragma clang loop unroll(disable)
                for (int k = 0; k < HIDDEN; ++k)
                    e = fmaf(fmaxf(fmaf(r, w1[k], b1[k]), 0.0f), w2[k], e);
            }
            res[u] = m ? e : 0.0f;
        }

        float4 o;
        o.x = res[0]; o.y = res[1]; o.z = res[2]; o.w = res[3];
        reinterpret_cast<float4*>(out)[g] = o;
    }
}

extern "C" void kernel_launch(void* const* d_in, const int* in_sizes, int n_in,
                              void* d_out, int out_size, void* d_ws, size_t ws_size,
                              hipStream_t stream) {
    const float* xyz  = (const float*)d_in[0];
    const float* cell = (const float*)d_in[1];
    const float* w1   = (const float*)d_in[2];
    const float* b1   = (const float*)d_in[3];
    const float* w2   = (const float*)d_in[4];
    const float* b2   = (const float*)d_in[5];
    float* out = (float*)d_out;

    const int N = in_sizes[0] / 3;                 // 2048
    int n4 = N >> 2;                               // 512, power of two
    int shift = 0;
    while ((1 << shift) < n4) ++shift;             // 9 for N=2048

    // 2048 blocks x 256 threads: fills 256 CUs at full wave occupancy in one
    // round; each thread produces 2 float4 groups (grid-stride).
    PairPot_kernel<<<2048, 256, 0, stream>>>(xyz, cell, w1, b1, w2, b2, out, N, shift);
}

// Round 3
// 11.665 us; speedup vs baseline: 1.1685x; 1.1685x over previous
//
#include <hip/hip_runtime.h>

#define HIDDEN 64

// PairPot: out[i*N+j] = mask ? MLP(|min_image(xyz[j]-xyz[i])|) : 0
//   mask = dis_sq < 2.5^2 && dis_sq != 0
// Fast path (b1==0, per-wave detect): MLP(r) = c*r + b2, c = sum_{w1k>0} w1k*w2k.
// Lean probe build: exact-fit grid, no loops/bounds checks, dense wave stores,
// raw v_sqrt_f32 (mask still decided on bit-exact dis_sq).
__global__ __launch_bounds__(256) void PairPot_kernel(
    const float* __restrict__ xyz, const float* __restrict__ cell,
    const float* __restrict__ w1, const float* __restrict__ b1,
    const float* __restrict__ w2, const float* __restrict__ b2,
    float* __restrict__ out, int N, int rowshift)   // threads/row = 1<<rowshift
{
    // ---- per-wave MLP collapse (HIDDEN == 64 == wave size), barrier-free ----
    const int lane = threadIdx.x & 63;
    const float w1k = w1[lane], b1k = b1[lane], w2k = w2[lane];
    float c = (w1k > 0.0f) ? __fmul_rn(w1k, w2k) : 0.0f;
    #pragma unroll
    for (int off = 32; off; off >>= 1) c += __shfl_xor(c, off, 64);
    const bool fast = (__ballot(b1k == 0.0f) == ~0ULL);
    const float b2v = b2[0];

    const float cx = cell[0], cy = cell[1], cz = cell[2];
    const float hx = __fmul_rn(0.5f, cx);
    const float hy = __fmul_rn(0.5f, cy);
    const float hz = __fmul_rn(0.5f, cz);

    const int tid  = blockIdx.x * 256 + threadIdx.x;
    const int i    = tid >> rowshift;                 // particle i (row)
    const int t    = tid & ((1 << rowshift) - 1);     // 0..(N/8-1)
    const int n4   = N >> 2;
    const int half = n4 >> 1;

    const float xi0 = xyz[3*i+0], xi1 = xyz[3*i+1], xi2 = xyz[3*i+2];
    float4* out4 = reinterpret_cast<float4*>(out) + (size_t)i * n4;

    // Two 4-particle groups per thread: g = t and g = t+half, so each wave's
    // 64 lanes store 64 CONSECUTIVE float4s (dense 1 KB) per store instruction.
    #pragma unroll
    for (int h = 0; h < 2; ++h) {
        const int g = t + h * half;
        const float4* pj = reinterpret_cast<const float4*>(xyz + 12 * g);
        const float4 va = pj[0], vb = pj[1], vc2 = pj[2];
        const float jx[4] = {va.x, va.w, vb.z, vc2.y};
        const float jy[4] = {va.y, vb.x, vb.w, vc2.z};
        const float jz[4] = {va.z, vb.y, vc2.x, vc2.w};

        float res[4];
        #pragma unroll
        for (int u = 0; u < 4; ++u) {
            // __f*_rn forbids fma contraction: mask decision bit-matches reference.
            float dx = __fsub_rn(jx[u], xi0);
            float dy = __fsub_rn(jy[u], xi1);
            float dz = __fsub_rn(jz[u], xi2);
            dx = __fadd_rn(dx, (dx >= hx) ? -cx : ((dx < -hx) ? cx : 0.0f));
            dy = __fadd_rn(dy, (dy >= hy) ? -cy : ((dy < -hy) ? cy : 0.0f));
            dz = __fadd_rn(dz, (dz >= hz) ? -cz : ((dz < -hz) ? cz : 0.0f));
            float s = __fadd_rn(__fadd_rn(__fmul_rn(dx, dx), __fmul_rn(dy, dy)),
                                __fmul_rn(dz, dz));
            const bool m = (s < 6.25f) && (s != 0.0f);
            float e;
            if (fast) {
                // raw v_sqrt_f32 (~1 ulp): value error ~3e-6 << 0.123 threshold
                e = fmaf(c, __builtin_amdgcn_sqrtf(s), b2v);
            } else {
                const float r = sqrtf(s);   // general fallback (not taken here)
                e = b2v;
                #pragma clang loop unroll(disable)
                for (int k = 0; k < HIDDEN; ++k)
                    e = fmaf(fmaxf(fmaf(r, w1[k], b1[k]), 0.0f), w2[k], e);
            }
            res[u] = m ? e : 0.0f;
        }
        out4[g] = make_float4(res[0], res[1], res[2], res[3]);
    }
}

extern "C" void kernel_launch(void* const* d_in, const int* in_sizes, int n_in,
                              void* d_out, int out_size, void* d_ws, size_t ws_size,
                              hipStream_t stream) {
    const float* xyz  = (const float*)d_in[0];
    const float* cell = (const float*)d_in[1];
    const float* w1   = (const float*)d_in[2];
    const float* b1   = (const float*)d_in[3];
    const float* w2   = (const float*)d_in[4];
    const float* b2   = (const float*)d_in[5];
    float* out = (float*)d_out;

    const int N = in_sizes[0] / 3;        // 2048
    const int tpr = N / 8;                // threads per row (256), power of two
    int rowshift = 0;
    while ((1 << rowshift) < tpr) ++rowshift;

    const int total_threads = N * tpr;    // one thread per 8 outputs
    PairPot_kernel<<<total_threads / 256, 256, 0, stream>>>(
        xyz, cell, w1, b1, w2, b2, out, N, rowshift);
}